// Round 1
// baseline (4359.018 us; speedup 1.0000x reference)
//
#include <hip/hip_runtime.h>
#include <hip/hip_bf16.h>

typedef __hip_bfloat16 bf16;
typedef short bf16x8 __attribute__((ext_vector_type(8)));
typedef float f32x4 __attribute__((ext_vector_type(4)));
typedef unsigned long long u64;
typedef unsigned int u32;

#define MFMA16(A, B, C) __builtin_amdgcn_mfma_f32_16x16x32_bf16(A, B, C, 0, 0, 0)

__device__ __forceinline__ float sigf(float x) { return 1.f / (1.f + __expf(-x)); }
__device__ __forceinline__ float tanh_fast(float x) { return 2.f / (1.f + __expf(-2.f * x)) - 1.f; }

// MALL-direct 16B load (two 8B system-relaxed atomics -> sc0 sc1; bypasses
// L1/L2 so poisoned/stale cached lines can never be observed).
__device__ __forceinline__ bf16x8 ld16(const u64* p) {
  u64 lo = __hip_atomic_load(p, __ATOMIC_RELAXED, __HIP_MEMORY_SCOPE_SYSTEM);
  u64 hi = __hip_atomic_load(p + 1, __ATOMIC_RELAXED, __HIP_MEMORY_SCOPE_SYSTEM);
  union { u64 q[2]; bf16x8 v; } u;
  u.q[0] = lo; u.q[1] = hi;
  return u.v;
}

__device__ __forceinline__ bf16x8 pack8(float4 f0, float4 f1) {
  union { short s[8]; bf16x8 v8; } o;
  o.s[0] = __builtin_bit_cast(short, __float2bfloat16(f0.x));
  o.s[1] = __builtin_bit_cast(short, __float2bfloat16(f0.y));
  o.s[2] = __builtin_bit_cast(short, __float2bfloat16(f0.z));
  o.s[3] = __builtin_bit_cast(short, __float2bfloat16(f0.w));
  o.s[4] = __builtin_bit_cast(short, __float2bfloat16(f1.x));
  o.s[5] = __builtin_bit_cast(short, __float2bfloat16(f1.y));
  o.s[6] = __builtin_bit_cast(short, __float2bfloat16(f1.z));
  o.s[7] = __builtin_bit_cast(short, __float2bfloat16(f1.w));
  return o.v8;
}

// ---------------- transpose+cast: WT[n][k] = bf16(W[k][n]) ----------------
__global__ __launch_bounds__(256) void transpose_k(const float* __restrict__ W,
                                                   bf16* __restrict__ WT,
                                                   int K, int N) {
  __shared__ bf16 tile[32][33];
  const int n0 = blockIdx.x * 32, k0 = blockIdx.y * 32;
  const int c = threadIdx.x & 31, r0 = threadIdx.x >> 5;
  for (int i = 0; i < 4; ++i) {
    int r = r0 + 8 * i;
    tile[r][c] = __float2bfloat16(W[(long)(k0 + r) * N + (n0 + c)]);
  }
  __syncthreads();
  for (int i = 0; i < 4; ++i) {
    int r = r0 + 8 * i;
    WT[(long)(n0 + r) * K + (k0 + c)] = tile[c][r];
  }
}

// ---------------- fused 2-layer persistent LSTM -----------------------------
// 256 WGs x 256 thr: (layer = bid>>7, bg = (bid>>5)&3, cg = bid&31).
// WG owns batch rows [16bg,16bg+16) x h-cols [16cg,16cg+16) (64 gate-cols).
// Wh B-fragments register-resident (64 VGPR/wave); Wi1 in swizzled LDS;
// Wi0 register-resident (32 VGPR). Waves split K 4-ways (wave kh owns
// k in [128kh,128kh+128)); each wave polls only its OWN 8 producers
// (intra-wave => no barrier between poll and gather) and gathers its
// K-quarter straight into A-frags (4 x ld16/lane). K-partials reduced via
// 20KB LDS zs; eltwise fully per-thread (1 c-value each). h slices are
// 512B, published by wave 0, release-sentinel per (t,bg,cg).
// hD layout: [t][bg 4][s 64][row 16][8] bf16, chunk s = 2*cg + sl.
__global__ __launch_bounds__(256, 1) void lstm2_fused_k(
    const float* __restrict__ x,  // [64][512][264] f32
    const bf16* __restrict__ WiT0, const bf16* __restrict__ WhT0,
    const float* __restrict__ bias0,
    const bf16* __restrict__ WiT1, const bf16* __restrict__ WhT1,
    const float* __restrict__ bias1,
    u64* __restrict__ h1D, u64* __restrict__ h2D,
    u32* __restrict__ sent)  // [2][512][4][32] u32, zeroed
{
  __shared__ __align__(16) short Wi1s[64 * 512];  // 64KB, XOR-swizzled (layer1)
  __shared__ float zs[4 * 64 * 20];               // 20KB K-partial staging
  __shared__ __align__(16) bf16 hstage[256];      // 512B publish staging

  const int layer = blockIdx.x >> 7;
  const int bg = (blockIdx.x >> 5) & 3;
  const int cg = blockIdx.x & 31;
  const int tid = threadIdx.x;
  const int lane = tid & 63;
  const int kh = tid >> 6;   // wave id = K-partition id
  const int q = lane >> 4;
  const int r = lane & 15;

  const bf16* WhT = layer ? WhT1 : WhT0;
  const float* bias = layer ? bias1 : bias0;
  u32* s0 = sent;
  u32* s1 = sent + 512 * 128;
  u32* smy = layer ? s1 : s0;
  u64* hown = layer ? h2D : h1D;

  // ---- Wh B-frags -> registers: wh[nt][kt], col = nt*512 + 16cg + r ----
  bf16x8 wh[4][4];
#pragma unroll
  for (int nt = 0; nt < 4; ++nt)
#pragma unroll
    for (int kt = 0; kt < 4; ++kt)
      wh[nt][kt] = *(const bf16x8*)(WhT + (long)(nt * 512 + cg * 16 + r) * 512 +
                                    (kh * 4 + kt) * 32 + q * 8);

  bf16x8 wi0r[4][2];  // layer-0 Wi frags (K=256), register-resident
  if (layer == 0) {
#pragma unroll
    for (int nt = 0; nt < 4; ++nt)
#pragma unroll
      for (int kt = 0; kt < 2; ++kt)
        wi0r[nt][kt] = *(const bf16x8*)(WiT0 + (long)(nt * 512 + cg * 16 + r) * 256 +
                                        (kh * 2 + kt) * 32 + q * 8);
  } else {
    // stage Wi1 slice to LDS, 16B-chunk XOR swizzle (chunk ^= j&7 -> 2-way max)
    char* wb = (char*)Wi1s;
    for (int idx = tid; idx < 64 * 64; idx += 256) {
      const int j = idx >> 6, kc = idx & 63;  // j = nt*16 + rr, kc = 16B chunk
      const int col = (j >> 4) * 512 + cg * 16 + (j & 15);
      *(bf16x8*)(wb + j * 1024 + ((kc ^ (j & 7)) * 16)) =
          *(const bf16x8*)(WiT1 + (long)col * 512 + kc * 8);
    }
  }

  // eltwise role: thread = (row erow, local h-col ec)
  const int erow = tid & 15, ec = tid >> 4;
  float br[4];
#pragma unroll
  for (int g = 0; g < 4; ++g) br[g] = bias[g * 512 + cg * 16 + ec];
  float creg = 0.f;

  __syncthreads();

#pragma unroll 1
  for (int t = 0; t < 512; ++t) {
    f32x4 acc[4];
#pragma unroll
    for (int nt = 0; nt < 4; ++nt) { acc[nt][0] = 0.f; acc[nt][1] = 0.f; acc[nt][2] = 0.f; acc[nt][3] = 0.f; }

    if (layer == 0) {
      // issue x loads first: latency hides under the poll
      const float* xrow = x + ((long)(16 * bg + r) * 512 + t) * 264;
      float4 xf[2][2];
#pragma unroll
      for (int kt = 0; kt < 2; ++kt) {
        const int f0 = (kh * 2 + kt) * 32 + q * 8;
        xf[kt][0] = *(const float4*)(xrow + f0);
        xf[kt][1] = *(const float4*)(xrow + f0 + 4);
      }
      if (t > 0 && lane < 8) {  // wave kh needs producers cg' in [8kh,8kh+8)
        const u32* sp = s0 + (long)(t - 1) * 128 + bg * 32 + kh * 8 + lane;
        while ((__ballot(__hip_atomic_load(sp, __ATOMIC_RELAXED,
                                           __HIP_MEMORY_SCOPE_SYSTEM) != 0) &
                0xffull) != 0xffull)
          __builtin_amdgcn_s_sleep(2);
      }
      bf16x8 ax[2];
#pragma unroll
      for (int kt = 0; kt < 2; ++kt) ax[kt] = pack8(xf[kt][0], xf[kt][1]);
#pragma unroll
      for (int nt = 0; nt < 4; ++nt)
#pragma unroll
        for (int kt = 0; kt < 2; ++kt)
          acc[nt] = MFMA16(ax[kt], wi0r[nt][kt], acc[nt]);
      if (t > 0) {
        bf16x8 ah[4];
#pragma unroll
        for (int kt = 0; kt < 4; ++kt) {
          const int s = (kh * 4 + kt) * 4 + q;
          ah[kt] = ld16(h1D + (((long)(t - 1) * 4 + bg) * 64 + s) * 32 + r * 2);
        }
#pragma unroll
        for (int nt = 0; nt < 4; ++nt)
#pragma unroll
          for (int kt = 0; kt < 4; ++kt)
            acc[nt] = MFMA16(ah[kt], wh[nt][kt], acc[nt]);
      }
    } else {
      // combined poll: lanes 0-7 -> h1[t] producers, lanes 8-15 -> h2[t-1]
      const u64 need = (t > 0) ? 0xffffull : 0xffull;
      if (lane < 16 && (t > 0 || lane < 8)) {
        const u32* sp;
        if (lane < 8) sp = s0 + (long)t * 128 + bg * 32 + kh * 8 + lane;
        else          sp = s1 + (long)(t - 1) * 128 + bg * 32 + kh * 8 + (lane - 8);
        while ((__ballot(__hip_atomic_load(sp, __ATOMIC_RELAXED,
                                           __HIP_MEMORY_SCOPE_SYSTEM) != 0) &
                need) != need)
          __builtin_amdgcn_s_sleep(2);
      }
      bf16x8 a2[4], a1[4];
      if (t > 0) {
#pragma unroll
        for (int kt = 0; kt < 4; ++kt) {
          const int s = (kh * 4 + kt) * 4 + q;
          a2[kt] = ld16(h2D + (((long)(t - 1) * 4 + bg) * 64 + s) * 32 + r * 2);
        }
      }
#pragma unroll
      for (int kt = 0; kt < 4; ++kt) {
        const int s = (kh * 4 + kt) * 4 + q;
        a1[kt] = ld16(h1D + (((long)t * 4 + bg) * 64 + s) * 32 + r * 2);
      }
      if (t > 0) {  // recurrence edge first: B in registers, zero LDS
#pragma unroll
        for (int nt = 0; nt < 4; ++nt)
#pragma unroll
          for (int kt = 0; kt < 4; ++kt)
            acc[nt] = MFMA16(a2[kt], wh[nt][kt], acc[nt]);
      }
      const char* wb = (const char*)Wi1s;
#pragma unroll
      for (int nt = 0; nt < 4; ++nt)
#pragma unroll
        for (int kt = 0; kt < 4; ++kt) {
          const int kc = (kh * 4 + kt) * 4 + q;
          const bf16x8 bfrag =
              *(const bf16x8*)(wb + (nt * 16 + r) * 1024 + ((kc ^ (r & 7)) * 16));
          acc[nt] = MFMA16(a1[kt], bfrag, acc[nt]);
        }
    }

    // K-partial staging: zs[kh][j = nt*16 + r][4q..4q+4) (stride 20 -> 2-way max)
#pragma unroll
    for (int nt = 0; nt < 4; ++nt)
      *(f32x4*)(zs + (kh * 64 + nt * 16 + r) * 20 + q * 4) = acc[nt];
    __syncthreads();

    float z[4];
#pragma unroll
    for (int g = 0; g < 4; ++g) {
      const float* zp = zs + (g * 16 + ec) * 20 + erow;
      z[g] = ((zp[0] + zp[1280]) + (zp[2560] + zp[3840])) + br[g];
    }
    const float cnew = sigf(z[1]) * creg + sigf(z[0]) * tanh_fast(z[2]);
    const float hnew = sigf(z[3]) * tanh_fast(cnew);
    creg = cnew;
    hstage[(ec >> 3) * 128 + erow * 8 + (ec & 7)] = __float2bfloat16(hnew);
    __syncthreads();

    // publish 512B slice (wave 0, lanes 0-31), then release sentinel
    if (tid < 32) {
      const u64* src = (const u64*)(hstage + tid * 8);
      u64* dst = hown + (((long)t * 4 + bg) * 64 + cg * 2 + (tid >> 4)) * 32 +
                 (tid & 15) * 2;
      __hip_atomic_store(dst, src[0], __ATOMIC_RELAXED, __HIP_MEMORY_SCOPE_SYSTEM);
      __hip_atomic_store(dst + 1, src[1], __ATOMIC_RELAXED, __HIP_MEMORY_SCOPE_SYSTEM);
    }
    if (tid == 0)
      __hip_atomic_store(smy + (long)t * 128 + bg * 32 + cg, 1u, __ATOMIC_RELEASE,
                         __HIP_MEMORY_SCOPE_AGENT);
    // keep next-step loads from hoisting above the release's vmcnt(0) drain
    asm volatile("" ::: "memory");
  }
}

// ---------------- dense head: concat -> 512 -> 256 -> 64 -> sigmoid ----------
__global__ __launch_bounds__(256) void head_k(
    const u64* __restrict__ h2D,  // [512][4][64][16][8] bf16; reads t=511
    const float* __restrict__ x,
    const float* __restrict__ Wd0, const float* __restrict__ bd0,
    const float* __restrict__ Wd1, const float* __restrict__ bd1,
    const float* __restrict__ Wf, const float* __restrict__ bfv,
    float* __restrict__ out) {
  const int b = blockIdx.x, tid = threadIdx.x;
  __shared__ float in0[520];
  __shared__ float d0s[512];
  __shared__ float d1s[256];
  if (tid < 64) {
    const int s = tid;  // chunk s = 2*cg + sl covers h-cols [8s, 8s+8)
    bf16x8 v = ld16(h2D + (((long)511 * 4 + (b >> 4)) * 64 + s) * 32 + (b & 15) * 2);
    union { bf16x8 v8; short sh[8]; } u;
    u.v8 = v;
    for (int j = 0; j < 8; ++j)
      in0[s * 8 + j] = __bfloat162float(__builtin_bit_cast(bf16, u.sh[j]));
  }
  if (tid < 8) in0[512 + tid] = x[((long)(b * 512 + 511)) * 264 + 256 + tid];
  __syncthreads();
  for (int j = tid; j < 512; j += 256) {
    float a = bd0[j];
    for (int k = 0; k < 520; ++k) a += in0[k] * Wd0[(long)k * 512 + j];
    d0s[j] = fmaxf(a, 0.f);
  }
  __syncthreads();
  if (tid < 256) {
    const int j = tid;
    float a = bd1[j];
    for (int k = 0; k < 512; ++k) a += d0s[k] * Wd1[(long)k * 256 + j];
    d1s[j] = fmaxf(a, 0.f);
  }
  __syncthreads();
  if (tid < 64) {
    const int j = tid;
    float a = bfv[j];
    for (int k = 0; k < 256; ++k) a += d1s[k] * Wf[(long)k * 64 + j];
    out[b * 64 + j] = sigf(a);
  }
}

extern "C" void kernel_launch(void* const* d_in, const int* in_sizes, int n_in,
                              void* d_out, int out_size, void* d_ws, size_t ws_size,
                              hipStream_t stream) {
  const float* x   = (const float*)d_in[0];
  const float* Wi0 = (const float*)d_in[1];
  const float* Wh0 = (const float*)d_in[2];
  const float* b0  = (const float*)d_in[3];
  const float* Wi1 = (const float*)d_in[4];
  const float* Wh1 = (const float*)d_in[5];
  const float* b1  = (const float*)d_in[6];
  const float* Wd0 = (const float*)d_in[7];
  const float* bd0 = (const float*)d_in[8];
  const float* Wd1 = (const float*)d_in[9];
  const float* bd1 = (const float*)d_in[10];
  const float* Wf  = (const float*)d_in[11];
  const float* bf_ = (const float*)d_in[12];
  float* out = (float*)d_out;

  char* ws = (char*)d_ws;
  size_t off = 0;
  auto carve = [&](size_t bytes) {
    void* p = ws + off;
    off += (bytes + 255) & ~(size_t)255;
    return p;
  };
  u32* sent = (u32*)carve((size_t)2 * 512 * 128 * 4);  // 512 KB sentinels
  const size_t zero_bytes = off;
  bf16* WiT0 = (bf16*)carve((size_t)2048 * 256 * 2);
  bf16* WhT0 = (bf16*)carve((size_t)2048 * 512 * 2);
  bf16* WiT1 = (bf16*)carve((size_t)2048 * 512 * 2);
  bf16* WhT1 = (bf16*)carve((size_t)2048 * 512 * 2);
  u64*  h1D  = (u64*)carve((size_t)512 * 64 * 64 * 16);  // 32 MB bf16 history
  u64*  h2D  = (u64*)carve((size_t)512 * 64 * 64 * 16);  // 32 MB bf16 history

  hipMemsetAsync(sent, 0, zero_bytes, stream);

  transpose_k<<<dim3(2048 / 32, 256 / 32), 256, 0, stream>>>(Wi0, WiT0, 256, 2048);
  transpose_k<<<dim3(2048 / 32, 512 / 32), 256, 0, stream>>>(Wh0, WhT0, 512, 2048);
  transpose_k<<<dim3(2048 / 32, 512 / 32), 256, 0, stream>>>(Wi1, WiT1, 512, 2048);
  transpose_k<<<dim3(2048 / 32, 512 / 32), 256, 0, stream>>>(Wh1, WhT1, 512, 2048);

  lstm2_fused_k<<<256, 256, 0, stream>>>(x, WiT0, WhT0, b0, WiT1, WhT1, b1,
                                         h1D, h2D, sent);

  head_k<<<64, 256, 0, stream>>>(h2D, x, Wd0, bd0, Wd1, bd1, Wf, bf_, out);
}

// Round 2
// 3236.943 us; speedup vs baseline: 1.3466x; 1.3466x over previous
//
#include <hip/hip_runtime.h>
#include <hip/hip_bf16.h>

typedef __hip_bfloat16 bf16;
typedef short bf16x8 __attribute__((ext_vector_type(8)));
typedef float f32x4 __attribute__((ext_vector_type(4)));
typedef unsigned long long u64;
typedef unsigned int u32;

#define MFMA16(A, B, C) __builtin_amdgcn_mfma_f32_16x16x32_bf16(A, B, C, 0, 0, 0)

__device__ __forceinline__ float sigf(float x) { return 1.f / (1.f + __expf(-x)); }
__device__ __forceinline__ float tanh_fast(float x) { return 2.f / (1.f + __expf(-2.f * x)) - 1.f; }

// MALL-direct 16B load (two 8B system-relaxed atomics -> sc0 sc1; bypasses
// L1/L2 so poisoned/stale cached lines can never be observed).
__device__ __forceinline__ bf16x8 ld16(const u64* p) {
  u64 lo = __hip_atomic_load(p, __ATOMIC_RELAXED, __HIP_MEMORY_SCOPE_SYSTEM);
  u64 hi = __hip_atomic_load(p + 1, __ATOMIC_RELAXED, __HIP_MEMORY_SCOPE_SYSTEM);
  union { u64 q[2]; bf16x8 v; } u;
  u.q[0] = lo; u.q[1] = hi;
  return u.v;
}

__device__ __forceinline__ bf16x8 pack8(float4 f0, float4 f1) {
  union { short s[8]; bf16x8 v8; } o;
  o.s[0] = __builtin_bit_cast(short, __float2bfloat16(f0.x));
  o.s[1] = __builtin_bit_cast(short, __float2bfloat16(f0.y));
  o.s[2] = __builtin_bit_cast(short, __float2bfloat16(f0.z));
  o.s[3] = __builtin_bit_cast(short, __float2bfloat16(f0.w));
  o.s[4] = __builtin_bit_cast(short, __float2bfloat16(f1.x));
  o.s[5] = __builtin_bit_cast(short, __float2bfloat16(f1.y));
  o.s[6] = __builtin_bit_cast(short, __float2bfloat16(f1.z));
  o.s[7] = __builtin_bit_cast(short, __float2bfloat16(f1.w));
  return o.v8;
}

// ---------------- transpose+cast: WT[n][k] = bf16(W[k][n]) ----------------
__global__ __launch_bounds__(256) void transpose_k(const float* __restrict__ W,
                                                   bf16* __restrict__ WT,
                                                   int K, int N) {
  __shared__ bf16 tile[32][33];
  const int n0 = blockIdx.x * 32, k0 = blockIdx.y * 32;
  const int c = threadIdx.x & 31, r0 = threadIdx.x >> 5;
  for (int i = 0; i < 4; ++i) {
    int r = r0 + 8 * i;
    tile[r][c] = __float2bfloat16(W[(long)(k0 + r) * N + (n0 + c)]);
  }
  __syncthreads();
  for (int i = 0; i < 4; ++i) {
    int r = r0 + 8 * i;
    WT[(long)(n0 + r) * K + (k0 + c)] = tile[c][r];
  }
}

// issue 16 A-chunk gathers (speculative; may read poison)
__device__ __forceinline__ void gather16_issue(const u64* __restrict__ mat, int m,
                                               int q, bf16x8* out) {
#pragma unroll
  for (int i = 0; i < 16; ++i) {
    const int s = i * 4 + q;
    out[i] = ld16(mat + ((long)(s << 6) + m) * 2);
  }
}

// self-validating retry: qword == 0xFF..FF (4x bf16 NaN, unreachable for
// h = sig*tanh in (-1,1)) means "not yet written"; each 8B store is atomic
// so a qword is either poison or complete. No fences/sentinels needed.
__device__ __forceinline__ void validate16(const u64* __restrict__ mat, int m,
                                           int q, bf16x8* out) {
#pragma unroll
  for (int i = 0; i < 16; ++i) {
    const u64* p = mat + ((long)((i * 4 + q) << 6) + m) * 2;
    union { bf16x8 v; u64 w[2]; } u;
    u.v = out[i];
    while (u.w[0] == ~0ull || u.w[1] == ~0ull) {
      __builtin_amdgcn_s_sleep(1);
      u.w[0] = __hip_atomic_load(p, __ATOMIC_RELAXED, __HIP_MEMORY_SCOPE_SYSTEM);
      u.w[1] = __hip_atomic_load(p + 1, __ATOMIC_RELAXED, __HIP_MEMORY_SCOPE_SYSTEM);
    }
    out[i] = u.v;
  }
}

// ---------------- fused 2-layer persistent LSTM, poisoned-data dataflow -----
// 128 WGs x 256 thr. layer = blk>>6, w = blk&63 owns h-cols [8w,8w+8).
// h1D/h2D: [512][64 slices][64 rows][8] bf16 (write-once, full history),
// pre-poisoned 0xFF. Producers publish with plain relaxed system stores
// (fire-and-forget, no release drain); consumers gather speculatively and
// retry poisoned qwords. Layer-1 issues both gathers (h1[t], h2[t-1])
// together and overlaps the Wi MFMAs with the h2 landing.
__global__ __launch_bounds__(256, 1) void lstm2_fused_k(
    const float* __restrict__ x,  // [64][512][264] f32
    const bf16* __restrict__ WiT0, const bf16* __restrict__ WhT0,
    const float* __restrict__ bias0,
    const bf16* __restrict__ WiT1, const bf16* __restrict__ WhT1,
    const float* __restrict__ bias1,
    u64* __restrict__ h1D, u64* __restrict__ h2D)
{
  __shared__ short Wis[32 * 520];
  __shared__ short Whs[32 * 520];
  __shared__ float zs[32 * 66];
  __shared__ __align__(16) bf16 hstage[64 * 8];

  const int layer = blockIdx.x >> 6;
  const int w = blockIdx.x & 63;
  const int tid = threadIdx.x;
  const int lane = tid & 63;
  const int wv = tid >> 6;
  const int q = lane >> 4;
  const int r = lane & 15;

  const int K_in = layer ? 512 : 256;
  const bf16* WiT = layer ? WiT1 : WiT0;
  const bf16* WhT = layer ? WhT1 : WhT0;
  const float* bias = layer ? bias1 : bias0;
  u64* houtD = layer ? h2D : h1D;

  // ---- stage weight slices into LDS (reused all 512 steps) ----
  for (int idx = tid; idx < 32 * 64; idx += 256) {
    const int j = idx >> 6, kc = idx & 63;
    const int zc = (j >> 3) * 512 + w * 8 + (j & 7);
    *(bf16x8*)(Whs + j * 520 + kc * 8) = *(const bf16x8*)(WhT + (long)zc * 512 + kc * 8);
  }
  const int csh = layer ? 6 : 5;
  const int cmask = (1 << csh) - 1;
  for (int idx = tid; idx < (32 << csh); idx += 256) {
    const int j = idx >> csh, kc = idx & cmask;
    const int zc = (j >> 3) * 512 + w * 8 + (j & 7);
    *(bf16x8*)(Wis + j * 520 + kc * 8) = *(const bf16x8*)(WiT + (long)zc * K_in + kc * 8);
  }

  const int m = wv * 16 + r;
  const short* wi0p = Wis + r * 520;
  const short* wi1p = Wis + (16 + r) * 520;
  const short* wh0p = Whs + r * 520;
  const short* wh1p = Whs + (16 + r) * 520;

  const int gb = tid & 63;
  const int gc0 = tid >> 6;
  float bias_r[2][4];
  for (int s = 0; s < 2; ++s)
    for (int g = 0; g < 4; ++g)
      bias_r[s][g] = bias[g * 512 + w * 8 + gc0 + 4 * s];
  float creg[2] = {0.f, 0.f};

  __syncthreads();

#pragma unroll 1
  for (int t = 0; t < 512; ++t) {
    f32x4 acc0 = {0.f, 0.f, 0.f, 0.f};
    f32x4 acc1 = {0.f, 0.f, 0.f, 0.f};

    if (layer == 0) {
      // issue x loads and the h1[t-1] gather first; pack/Wi-MFMA VALU work
      // hides the MALL latency
      const float* row = x + ((long)m * 512 + t) * 264;
      float4 xf0[8], xf1[8];
#pragma unroll
      for (int i = 0; i < 8; ++i) {
        xf0[i] = *(const float4*)(row + i * 32 + q * 8);
        xf1[i] = *(const float4*)(row + i * 32 + q * 8 + 4);
      }
      bf16x8 ah[16];
      if (t > 0) gather16_issue(h1D + (long)(t - 1) * 8192, m, q, ah);
#pragma unroll
      for (int i = 0; i < 8; ++i) {
        const bf16x8 ax = pack8(xf0[i], xf1[i]);
        const int kk = i * 32;
        acc0 = MFMA16(ax, *(const bf16x8*)(wi0p + kk + q * 8), acc0);
        acc1 = MFMA16(ax, *(const bf16x8*)(wi1p + kk + q * 8), acc1);
      }
      if (t > 0) {
        validate16(h1D + (long)(t - 1) * 8192, m, q, ah);
#pragma unroll
        for (int i = 0; i < 16; ++i) {
          const int kk = i * 32;
          acc0 = MFMA16(ah[i], *(const bf16x8*)(wh0p + kk + q * 8), acc0);
          acc1 = MFMA16(ah[i], *(const bf16x8*)(wh1p + kk + q * 8), acc1);
        }
      }
    } else {
      // issue BOTH gathers, then overlap Wi MFMAs with the h2 landing
      bf16x8 ax[16], ah[16];
      gather16_issue(h1D + (long)t * 8192, m, q, ax);
      if (t > 0) gather16_issue(h2D + (long)(t - 1) * 8192, m, q, ah);
      validate16(h1D + (long)t * 8192, m, q, ax);
#pragma unroll
      for (int i = 0; i < 16; ++i) {
        const int kk = i * 32;
        acc0 = MFMA16(ax[i], *(const bf16x8*)(wi0p + kk + q * 8), acc0);
        acc1 = MFMA16(ax[i], *(const bf16x8*)(wi1p + kk + q * 8), acc1);
      }
      if (t > 0) {
        validate16(h2D + (long)(t - 1) * 8192, m, q, ah);
#pragma unroll
        for (int i = 0; i < 16; ++i) {
          const int kk = i * 32;
          acc0 = MFMA16(ah[i], *(const bf16x8*)(wh0p + kk + q * 8), acc0);
          acc1 = MFMA16(ah[i], *(const bf16x8*)(wh1p + kk + q * 8), acc1);
        }
      }
    }

    // D-layout: row(b)=wv*16+q*4+i, col(n)=ntile*16+r  [m89-verified]
    {
      const int brow = wv * 16 + q * 4;
      for (int i = 0; i < 4; ++i) zs[r * 66 + brow + i] = acc0[i];
      for (int i = 0; i < 4; ++i) zs[(16 + r) * 66 + brow + i] = acc1[i];
    }
    __syncthreads();

    for (int s = 0; s < 2; ++s) {
      const int c = gc0 + 4 * s;
      const float zi = zs[(c)*66 + gb] + bias_r[s][0];
      const float zf = zs[(8 + c) * 66 + gb] + bias_r[s][1];
      const float zg = zs[(16 + c) * 66 + gb] + bias_r[s][2];
      const float zo = zs[(24 + c) * 66 + gb] + bias_r[s][3];
      const float cnew = sigf(zf) * creg[s] + sigf(zi) * tanh_fast(zg);
      const float hnew = sigf(zo) * tanh_fast(cnew);
      creg[s] = cnew;
      hstage[gb * 8 + c] = __float2bfloat16(hnew);
    }
    __syncthreads();

    // publish: fire-and-forget relaxed system stores (data IS the signal;
    // each 8B store is atomic, consumers retry on the poison pattern)
    if (tid < 64) {
      const u64* src = (const u64*)(hstage + tid * 8);
      u64* dst = houtD + (((long)t * 64 + w) * 64 + tid) * 2;
      __hip_atomic_store(dst, src[0], __ATOMIC_RELAXED, __HIP_MEMORY_SCOPE_SYSTEM);
      __hip_atomic_store(dst + 1, src[1], __ATOMIC_RELAXED, __HIP_MEMORY_SCOPE_SYSTEM);
    }
  }
}

// ---------------- dense head: concat -> 512 -> 256 -> 64 -> sigmoid ----------
__global__ __launch_bounds__(256) void head_k(
    const u64* __restrict__ h2D,  // [512][64][64][8] bf16; reads t=511
    const float* __restrict__ x,
    const float* __restrict__ Wd0, const float* __restrict__ bd0,
    const float* __restrict__ Wd1, const float* __restrict__ bd1,
    const float* __restrict__ Wf, const float* __restrict__ bfv,
    float* __restrict__ out) {
  const int b = blockIdx.x, tid = threadIdx.x;
  __shared__ float in0[520];
  __shared__ float d0s[512];
  __shared__ float d1s[256];
  if (tid < 64) {
    const int s = tid;
    bf16x8 v = ld16(h2D + (((long)511 * 64 + s) * 64 + b) * 2);
    union { bf16x8 v8; short sh[8]; } u;
    u.v8 = v;
    for (int j = 0; j < 8; ++j)
      in0[s * 8 + j] = __bfloat162float(__builtin_bit_cast(bf16, u.sh[j]));
  }
  if (tid < 8) in0[512 + tid] = x[((long)(b * 512 + 511)) * 264 + 256 + tid];
  __syncthreads();
  for (int j = tid; j < 512; j += 256) {
    float a = bd0[j];
    for (int k = 0; k < 520; ++k) a += in0[k] * Wd0[(long)k * 512 + j];
    d0s[j] = fmaxf(a, 0.f);
  }
  __syncthreads();
  if (tid < 256) {
    const int j = tid;
    float a = bd1[j];
    for (int k = 0; k < 512; ++k) a += d0s[k] * Wd1[(long)k * 256 + j];
    d1s[j] = fmaxf(a, 0.f);
  }
  __syncthreads();
  if (tid < 64) {
    const int j = tid;
    float a = bfv[j];
    for (int k = 0; k < 256; ++k) a += d1s[k] * Wf[(long)k * 64 + j];
    out[b * 64 + j] = sigf(a);
  }
}

extern "C" void kernel_launch(void* const* d_in, const int* in_sizes, int n_in,
                              void* d_out, int out_size, void* d_ws, size_t ws_size,
                              hipStream_t stream) {
  const float* x   = (const float*)d_in[0];
  const float* Wi0 = (const float*)d_in[1];
  const float* Wh0 = (const float*)d_in[2];
  const float* b0  = (const float*)d_in[3];
  const float* Wi1 = (const float*)d_in[4];
  const float* Wh1 = (const float*)d_in[5];
  const float* b1  = (const float*)d_in[6];
  const float* Wd0 = (const float*)d_in[7];
  const float* bd0 = (const float*)d_in[8];
  const float* Wd1 = (const float*)d_in[9];
  const float* bd1 = (const float*)d_in[10];
  const float* Wf  = (const float*)d_in[11];
  const float* bf_ = (const float*)d_in[12];
  float* out = (float*)d_out;

  char* ws = (char*)d_ws;
  size_t off = 0;
  auto carve = [&](size_t bytes) {
    void* p = ws + off;
    off += (bytes + 255) & ~(size_t)255;
    return p;
  };
  bf16* WiT0 = (bf16*)carve((size_t)2048 * 256 * 2);
  bf16* WhT0 = (bf16*)carve((size_t)2048 * 512 * 2);
  bf16* WiT1 = (bf16*)carve((size_t)2048 * 512 * 2);
  bf16* WhT1 = (bf16*)carve((size_t)2048 * 512 * 2);
  u64*  h1D  = (u64*)carve((size_t)512 * 64 * 64 * 16);  // 32 MB bf16 history
  u64*  h2D  = (u64*)carve((size_t)512 * 64 * 64 * 16);  // 32 MB bf16 history

  // poison both h histories: 0xFF bytes = bf16 NaN = "not yet written"
  hipMemsetAsync(h1D, 0xFF, (size_t)2 * 512 * 64 * 64 * 16, stream);

  transpose_k<<<dim3(2048 / 32, 256 / 32), 256, 0, stream>>>(Wi0, WiT0, 256, 2048);
  transpose_k<<<dim3(2048 / 32, 512 / 32), 256, 0, stream>>>(Wh0, WhT0, 512, 2048);
  transpose_k<<<dim3(2048 / 32, 512 / 32), 256, 0, stream>>>(Wi1, WiT1, 512, 2048);
  transpose_k<<<dim3(2048 / 32, 512 / 32), 256, 0, stream>>>(Wh1, WhT1, 512, 2048);

  lstm2_fused_k<<<128, 256, 0, stream>>>(x, WiT0, WhT0, b0, WiT1, WhT1, b1,
                                         h1D, h2D);

  head_k<<<64, 256, 0, stream>>>(h2D, x, Wd0, bd0, Wd1, bd1, Wf, bf_, out);
}